// Round 12
// baseline (575.368 us; speedup 1.0000x reference)
//
#include <hip/hip_runtime.h>

typedef unsigned short u16;
typedef unsigned int   u32;
typedef __bf16 bf16x8 __attribute__((ext_vector_type(8)));
typedef float  f32x4  __attribute__((ext_vector_type(4)));
typedef u32    u32x4  __attribute__((ext_vector_type(4)));
typedef u32    u32x2  __attribute__((ext_vector_type(2)));
typedef u16    u16x4  __attribute__((ext_vector_type(4)));

#define V_N   6890
#define V_PAD 6912
#define SQ2H  0.70710678118654752f

__device__ __forceinline__ float bf2f(u32 h) {
  union { u32 u; float f; } c; c.u = h << 16; return c.f;
}
__device__ __forceinline__ u16 f2bf(float f) {
  union { float f; u32 u; } c; c.f = f;
  return (u16)((c.u + 0x7fffu + ((c.u >> 16) & 1u)) >> 16);
}
__device__ __forceinline__ u32 pk(float lo, float hi) {
  return (u32)f2bf(lo) | ((u32)f2bf(hi) << 16);
}
__device__ __forceinline__ void gload_lds16(const void* g, void* l) {
  __builtin_amdgcn_global_load_lds((const __attribute__((address_space(1))) void*)g,
                                   (__attribute__((address_space(3))) void*)l, 16, 0, 0);
}

// rfft8: X[k] = sum_a x[a] e^{-2pi i k a/8}; returns Z0, (Re,Im) k=1..3, Z4.
__device__ __forceinline__ void rfft8(const float* x, float& Z0, float& Re1, float& Im1,
                                      float& Re2, float& Im2, float& Re3, float& Im3, float& Z4) {
  float s04 = x[0] + x[4], d04 = x[0] - x[4];
  float s26 = x[2] + x[6], d26 = x[2] - x[6];
  float s15 = x[1] + x[5], d15 = x[1] - x[5];
  float s37 = x[3] + x[7], d37 = x[3] - x[7];
  float e = s04 + s26, f = s15 + s37;
  Z0 = e + f; Z4 = e - f;
  Re2 = s04 - s26; Im2 = s37 - s15;
  float t1 = SQ2H * (d15 - d37), t2 = SQ2H * (d15 + d37);
  Re1 = d04 + t1; Re3 = d04 - t1;
  Im1 = -(t2 + d26); Im3 = d26 - t2;
}

// ---- template FFT worker (one (t,r,c4) element or pad-zero tail) ----
__device__ __forceinline__ void do_trot(int g, const float* __restrict__ T, u16* __restrict__ B,
                                        int Tn, int Cc, int C4, int K0pad, int K1,
                                        int total, int pad) {
  if (g >= total) {
    int g2 = g - total;
    int padTot = Tn * pad;
    if (g2 >= padTot) return;
    int p = g2 % pad; int t = g2 / pad;
    size_t b4off = (size_t)Tn * K0pad + (size_t)6 * Tn * K1;
    size_t o = (size_t)t * K0pad + (K0pad - pad) + p;
    B[o] = 0; B[b4off + o] = 0;
    return;
  }
  int c4 = g % C4; int q = g / C4;
  int r = q % 5; int t = q / 5;
  float hs[8][4];
#pragma unroll
  for (int a = 0; a < 8; ++a) {
    f32x4 va = *(const f32x4*)(T + ((size_t)((t * 5 + r) * 8 + a)) * Cc + c4 * 4);
#pragma unroll
    for (int j = 0; j < 4; ++j) hs[a][j] = va[j];
  }
  float Z0[4], Z4[4], Re[3][4], Im[3][4];
#pragma unroll
  for (int ch = 0; ch < 4; ++ch) {
    float x[8];
#pragma unroll
    for (int a = 0; a < 8; ++a) x[a] = hs[a][ch];
    float z0, r1, i1, r2, i2, r3, i3, z4;
    rfft8(x, z0, r1, i1, r2, i2, r3, i3, z4);
    Z0[ch] = z0 * 0.125f; Z4[ch] = z4 * 0.125f;
    Re[0][ch] = r1 * 0.25f; Im[0][ch] = i1 * 0.25f;
    Re[1][ch] = r2 * 0.25f; Im[1][ch] = i2 * 0.25f;
    Re[2][ch] = r3 * 0.25f; Im[2][ch] = i3 * 0.25f;
  }
  int cb = c4 * 4;
  u32x2 w0v; w0v[0] = pk(Z0[0], Z0[1]); w0v[1] = pk(Z0[2], Z0[3]);
  *(u32x2*)(B + (size_t)t * K0pad + r * Cc + cb) = w0v;
  size_t bo1 = (size_t)Tn * K0pad;
  size_t binSz = (size_t)2 * Tn * K1;
  int off = ((r * Cc + cb) << 1);
#pragma unroll
  for (int k = 0; k < 3; ++k) {
    u32x4 wr, wi;
#pragma unroll
    for (int j = 0; j < 4; ++j) {
      wr[j] = pk(Re[k][j], Im[k][j]);
      wi[j] = pk(-Im[k][j], Re[k][j]);
    }
    *(u32x4*)(B + bo1 + k * binSz + (size_t)t * K1 + off) = wr;
    *(u32x4*)(B + bo1 + k * binSz + (size_t)(Tn + t) * K1 + off) = wi;
  }
  u32x2 w4v; w4v[0] = pk(Z4[0], Z4[1]); w4v[1] = pk(Z4[2], Z4[3]);
  *(u32x2*)(B + bo1 + 3 * binSz + (size_t)t * K0pad + r * Cc + cb) = w4v;
}

// ---- single fused prep dispatch: cvt | trot L0 | trot L1 | trot L2 | wdt ----
__global__ void prep_kernel(const float* __restrict__ signal, u16* __restrict__ sigbf, int nCvt,
                            const float* __restrict__ T0, u16* __restrict__ B0,
                            const float* __restrict__ T1, u16* __restrict__ B1,
                            const float* __restrict__ T2, u16* __restrict__ B2,
                            const float* __restrict__ Wd, u16* __restrict__ wdtB,
                            int o1, int o2, int o3, int o4) {
  int b = blockIdx.x;
  if (b < o1) {
    int g = b * 256 + threadIdx.x;
    if (g >= nCvt) return;
    f32x4 v = *(const f32x4*)(signal + (size_t)g * 4);
    u16x4 o; o.x = f2bf(v.x); o.y = f2bf(v.y); o.z = f2bf(v.z); o.w = f2bf(v.w);
    *(u16x4*)(sigbf + (size_t)g * 4) = o;
  } else if (b < o2) {
    int g = (b - o1) * 256 + threadIdx.x;
    do_trot(g, T0, B0, 96, 544, 136, 2752, 5440, 96 * 5 * 136, 32);
  } else if (b < o3) {
    int g = (b - o2) * 256 + threadIdx.x;
    do_trot(g, T1, B1, 128, 96, 24, 512, 960, 128 * 5 * 24, 32);
  } else if (b < o4) {
    int g = (b - o3) * 256 + threadIdx.x;
    do_trot(g, T2, B2, 128, 128, 32, 640, 1280, 128 * 5 * 32, 0);
  } else {
    int g = (b - o4) * 256 + threadIdx.x;
    if (g >= V_PAD * 128) return;
    int k = g & 127, n = g >> 7;
    float v = (n < V_N) ? Wd[(size_t)k * V_N + n] : 0.f;
    u16 hi = f2bf(v);
    wdtB[(size_t)n * 256 + k] = hi;
    wdtB[(size_t)n * 256 + 128 + k] = f2bf(v - bf2f(hi));
  }
}

// ---- barycentric gather + interp + rfft8 over angular axis; writes A_hat sections.
//      idx/wgt rows are 24 consecutive elements (96B, 16B-aligned): vec4 loads. ----
__global__ void interp_fft_kernel(const u16* __restrict__ sig, int Cc, int C8,
                                  const int* __restrict__ idx, const float* __restrict__ wgt,
                                  u16* __restrict__ out, int v0, int Kpad, int K0pad, int K1,
                                  int total) {
  int g = blockIdx.x * 256 + threadIdx.x;
  if (g >= total) return;
  int c8 = g % C8; int q = g / C8;
  int r = q % 5; int vr = q / 5;
  size_t ib = ((size_t)((v0 + vr) * 5 + r)) * 24;
  u32x4 iv[6]; f32x4 wv[6];
  const u32x4* ip = (const u32x4*)(idx + ib);
  const f32x4* wp = (const f32x4*)(wgt + ib);
#pragma unroll
  for (int m = 0; m < 6; ++m) { iv[m] = ip[m]; wv[m] = wp[m]; }
  float xs[8][8];
#pragma unroll
  for (int a = 0; a < 8; ++a) {
    const int e = a * 3;
    int i0 = iv[e >> 2][e & 3], i1 = iv[(e + 1) >> 2][(e + 1) & 3], i2 = iv[(e + 2) >> 2][(e + 2) & 3];
    float w0 = wv[e >> 2][e & 3], w1 = wv[(e + 1) >> 2][(e + 1) & 3], w2 = wv[(e + 2) >> 2][(e + 2) & 3];
    u32x4 s0 = *(const u32x4*)(sig + (size_t)i0 * Cc + c8 * 8);
    u32x4 s1 = *(const u32x4*)(sig + (size_t)i1 * Cc + c8 * 8);
    u32x4 s2 = *(const u32x4*)(sig + (size_t)i2 * Cc + c8 * 8);
#pragma unroll
    for (int j = 0; j < 4; ++j) {
      xs[a][2 * j]     = w0 * bf2f(s0[j] & 0xffffu) + w1 * bf2f(s1[j] & 0xffffu) + w2 * bf2f(s2[j] & 0xffffu);
      xs[a][2 * j + 1] = w0 * bf2f(s0[j] >> 16)     + w1 * bf2f(s1[j] >> 16)     + w2 * bf2f(s2[j] >> 16);
    }
  }
  float Z0[8], Z4[8], Re1[8], Im1[8], Re2[8], Im2[8], Re3[8], Im3[8];
#pragma unroll
  for (int ch = 0; ch < 8; ++ch) {
    float x[8];
#pragma unroll
    for (int a = 0; a < 8; ++a) x[a] = xs[a][ch];
    rfft8(x, Z0[ch], Re1[ch], Im1[ch], Re2[ch], Im2[ch], Re3[ch], Im3[ch], Z4[ch]);
  }
  size_t rowb = (size_t)vr * Kpad;
  int cb = c8 * 8;
  u32x4 a0, a4;
#pragma unroll
  for (int p = 0; p < 4; ++p) {
    a0[p] = pk(Z0[2 * p], Z0[2 * p + 1]);
    a4[p] = pk(Z4[2 * p], Z4[2 * p + 1]);
  }
  *(u32x4*)(out + rowb + r * Cc + cb) = a0;
  *(u32x4*)(out + rowb + K0pad + 3 * K1 + r * Cc + cb) = a4;
  int off1 = K0pad + ((r * Cc + cb) << 1);
  u32x4 wa, wb;
#pragma unroll
  for (int j = 0; j < 4; ++j) { wa[j] = pk(Re1[j], Im1[j]); wb[j] = pk(Re1[4 + j], Im1[4 + j]); }
  *(u32x4*)(out + rowb + off1) = wa;
  *(u32x4*)(out + rowb + off1 + 8) = wb;
#pragma unroll
  for (int j = 0; j < 4; ++j) { wa[j] = pk(Re2[j], Im2[j]); wb[j] = pk(Re2[4 + j], Im2[4 + j]); }
  *(u32x4*)(out + rowb + off1 + K1) = wa;
  *(u32x4*)(out + rowb + off1 + K1 + 8) = wb;
#pragma unroll
  for (int j = 0; j < 4; ++j) { wa[j] = pk(Re3[j], Im3[j]); wb[j] = pk(Re3[4 + j], Im3[4 + j]); }
  *(u32x4*)(out + rowb + off1 + 2 * K1) = wa;
  *(u32x4*)(out + rowb + off1 + 2 * K1 + 8) = wb;
}

// ---- split-K reduce + 8-point iFFT + relu(+bias) + angular max; optional split-bf16 out ----
__global__ void amp_fft(const float* __restrict__ Cin, size_t cstride,
                        const float* __restrict__ bias, u16* __restrict__ out,
                        int Tn, int ldo, int split,
                        int ns0, int ns1, int ns2, int ns3, int ns4, int total) {
  int g = blockIdx.x * 256 + threadIdx.x;
  if (g >= total) return;
  int t = g % Tn, v = g / Tn;
  const int nsA[8] = {ns0, ns1, ns1, ns2, ns2, ns3, ns3, ns4};
  float sec[8];
  size_t base = (size_t)v * (8 * Tn) + t;
#pragma unroll
  for (int s = 0; s < 8; ++s) {
    const float* p = Cin + base + s * Tn;
    float a = p[0];
    for (int k = 1; k < nsA[s]; ++k) a += p[(size_t)k * cstride];
    sec[s] = a;
  }
  const float Ct[8] = {1.f, SQ2H, 0.f, -SQ2H, -1.f, -SQ2H, 0.f, SQ2H};
  const float St[8] = {0.f, SQ2H, 1.f, SQ2H, 0.f, -SQ2H, -1.f, -SQ2H};
  float m;
#pragma unroll
  for (int o = 0; o < 8; ++o) {
    float val = sec[0] + ((o & 1) ? -sec[7] : sec[7])
      + sec[1] * Ct[o]           - sec[2] * St[o]
      + sec[3] * Ct[(2 * o) & 7] - sec[4] * St[(2 * o) & 7]
      + sec[5] * Ct[(3 * o) & 7] - sec[6] * St[(3 * o) & 7];
    m = (o == 0) ? val : fmaxf(m, val);
  }
  m = fmaxf(m + bias[t], 0.f);
  u16 hi = f2bf(m);
  out[(size_t)v * ldo + t] = hi;
  if (split) out[(size_t)v * ldo + Tn + t] = f2bf(m - bf2f(hi));
}

// ---- grouped 256-row bf16 GEMM (R7-proven schedule). Per-group nh flag:
//      nh=0: 256-wide tile (2Mx4N waves, 64 MFMA/Ktile, stage 8, vmcnt(8))
//      nh=1: 128-wide tile (4Mx2N waves, 32 MFMA/Ktile, stage 6, vmcnt(6)) ----
struct GTab {
  int start[6];
  int aOff[5];
  int bOff[5];
  int cOff[5];
  int Kg[5];
  int kch[5];
  int ntn[5];
  int Nv[5];
  int nh[5];
};

__global__ __launch_bounds__(512, 2) void gemm_grp(
    const u16* __restrict__ A, int lda, const u16* __restrict__ Bbase,
    float* __restrict__ C, int ldc, size_t cstride,
    const float* __restrict__ bias, int Mvalid, int ntm, int nG, GTab tb) {
  __shared__ __align__(16) u16 lA[2][256 * 64];
  __shared__ __align__(16) u16 lB[2][256 * 64];
  const int tid = threadIdx.x;
  const int w = tid >> 6, l = tid & 63;

  const int nb = gridDim.x, bid = blockIdx.x;
  const int qq = nb >> 3, rr = nb & 7;
  const int xcd = bid & 7, ii = bid >> 3;
  const int vb = (xcd < rr ? xcd * (qq + 1) : rr * (qq + 1) + (xcd - rr) * qq) + ii;

  int gI = 0;
#pragma unroll
  for (int k = 1; k < 5; ++k) if (k < nG && vb >= tb.start[k]) gI = k;
  const int local = vb - tb.start[gI];
  const int ntnG = tb.ntn[gI];
  const int per = ntm * ntnG;
  const int s = local / per;
  const int rem = local - s * per;
  const int tm = rem / ntnG, tn = rem - tm * ntnG;
  const int Kg = tb.Kg[gI];
  const int kb = s * tb.kch[gI];
  int ke = kb + tb.kch[gI]; if (ke > Kg) ke = Kg;
  const int nt = (ke - kb + 63) >> 6;
  const int Nv = tb.Nv[gI];
  const int cO = tb.cOff[gI];
  const int nh = tb.nh[gI];
  const int ldb = Kg;
  float* Cb = C + (size_t)s * cstride;

  const u16* Ab = A + (size_t)(tm * 256) * lda + tb.aOff[gI] + kb;
  const u16* Bb = Bbase + tb.bOff[gI] + (size_t)(tn * (nh ? 128 : 256)) * ldb + kb;

  const int srow = tid >> 3;
  const int scol = (((l & 7) ^ (srow & 7)) << 3);
  u16* laBase = &lA[0][0];
  u16* lbBase = &lB[0][0];

  f32x4 acc[8][4];
#pragma unroll
  for (int i = 0; i < 8; ++i)
#pragma unroll
    for (int j = 0; j < 4; ++j) acc[i][j] = (f32x4){0.f, 0.f, 0.f, 0.f};

  const int ksel = l >> 4, swz = l & 7;
  const int kc0 = ((ksel ^ swz) << 3);
  const int kc1 = (((4 + ksel) ^ swz) << 3);

  if (nh) {
    // ---------------- narrow: 128-wide tile, 4Mx2N waves ----------------
    const int wm = w >> 1, wn = w & 1;
    const int aoffbase = (wm * 64 + (l & 15)) * 64;
    const int boffbase = (wn * 64 + (l & 15)) * 64;
    auto STAGE = [&](int buf, int k0) {
      const u16* ga = Ab + (size_t)srow * lda + k0 + scol;
      const u16* gb = Bb + (size_t)srow * ldb + k0 + scol;
      u16* la = laBase + buf * (256 * 64) + w * 512;
      u16* lb = lbBase + buf * (256 * 64) + w * 512;
#pragma unroll
      for (int i = 0; i < 4; ++i)
        gload_lds16(ga + (size_t)(i * 64) * lda, la + i * 4096);
#pragma unroll
      for (int i = 0; i < 2; ++i)
        gload_lds16(gb + (size_t)(i * 64) * ldb, lb + i * 4096);
    };
    STAGE(0, 0);
    int cur = 0;
    for (int t = 0; t < nt; ++t) {
      if (t + 1 < nt) STAGE(cur ^ 1, (t + 1) * 64);
      __builtin_amdgcn_sched_barrier(0);
      if (t + 1 < nt) { asm volatile("s_waitcnt vmcnt(6)" ::: "memory"); }
      else            { asm volatile("s_waitcnt vmcnt(0)" ::: "memory"); }
      __builtin_amdgcn_s_barrier();
      __builtin_amdgcn_sched_barrier(0);
      const u16* lab = laBase + cur * (256 * 64);
      const u16* lbb = lbBase + cur * (256 * 64);
#pragma unroll
      for (int kk = 0; kk < 2; ++kk) {
        const int kc = kk ? kc1 : kc0;
        bf16x8 bfr[4];
#pragma unroll
        for (int ni = 0; ni < 4; ++ni)
          bfr[ni] = *(const bf16x8*)&lbb[boffbase + ni * 1024 + kc];
        bf16x8 afr[4];
#pragma unroll
        for (int mi = 0; mi < 4; ++mi)
          afr[mi] = *(const bf16x8*)&lab[aoffbase + mi * 1024 + kc];
        __builtin_amdgcn_s_setprio(1);
#pragma unroll
        for (int mi = 0; mi < 4; ++mi)
#pragma unroll
          for (int ni = 0; ni < 4; ++ni)
            acc[mi][ni] =
                __builtin_amdgcn_mfma_f32_16x16x32_bf16(afr[mi], bfr[ni], acc[mi][ni], 0, 0, 0);
        __builtin_amdgcn_s_setprio(0);
      }
      __builtin_amdgcn_sched_barrier(0);
      __builtin_amdgcn_s_barrier();
      cur ^= 1;
    }
    const int row0 = tm * 256 + wm * 64 + ((l >> 4) << 2);
    const int col0 = tn * 128 + wn * 64 + (l & 15);
#pragma unroll
    for (int mi = 0; mi < 4; ++mi) {
#pragma unroll
      for (int j = 0; j < 4; ++j) {
        int grow = row0 + mi * 16 + j;
        if (grow < Mvalid) {
#pragma unroll
          for (int ni = 0; ni < 4; ++ni) {
            int gcol = col0 + ni * 16;
            if (gcol < Nv) {
              float vv = acc[mi][ni][j];
              int gc = cO + gcol;
              if (bias) vv += bias[gc];
              Cb[(size_t)grow * ldc + gc] = vv;
            }
          }
        }
      }
    }
  } else {
    // ---------------- wide: 256-wide tile, 2Mx4N waves ----------------
    const int wm = w >> 2, wn = w & 3;
    const int aoffbase = (wm * 128 + (l & 15)) * 64;
    const int boffbase = (wn * 64 + (l & 15)) * 64;
    auto STAGE = [&](int buf, int k0) {
      const u16* ga = Ab + (size_t)srow * lda + k0 + scol;
      const u16* gb = Bb + (size_t)srow * ldb + k0 + scol;
      u16* la = laBase + buf * (256 * 64) + w * 512;
      u16* lb = lbBase + buf * (256 * 64) + w * 512;
#pragma unroll
      for (int i = 0; i < 4; ++i) {
        gload_lds16(ga + (size_t)(i * 64) * lda, la + i * 4096);
        gload_lds16(gb + (size_t)(i * 64) * ldb, lb + i * 4096);
      }
    };
    STAGE(0, 0);
    int cur = 0;
    for (int t = 0; t < nt; ++t) {
      if (t + 1 < nt) STAGE(cur ^ 1, (t + 1) * 64);
      __builtin_amdgcn_sched_barrier(0);
      if (t + 1 < nt) { asm volatile("s_waitcnt vmcnt(8)" ::: "memory"); }
      else            { asm volatile("s_waitcnt vmcnt(0)" ::: "memory"); }
      __builtin_amdgcn_s_barrier();
      __builtin_amdgcn_sched_barrier(0);
      const u16* lab = laBase + cur * (256 * 64);
      const u16* lbb = lbBase + cur * (256 * 64);
#pragma unroll
      for (int kk = 0; kk < 2; ++kk) {
        const int kc = kk ? kc1 : kc0;
        bf16x8 bfr[4];
#pragma unroll
        for (int ni = 0; ni < 4; ++ni)
          bfr[ni] = *(const bf16x8*)&lbb[boffbase + ni * 1024 + kc];
#pragma unroll
        for (int mh = 0; mh < 2; ++mh) {
          bf16x8 afr[4];
#pragma unroll
          for (int mi = 0; mi < 4; ++mi)
            afr[mi] = *(const bf16x8*)&lab[aoffbase + (mh * 4 + mi) * 1024 + kc];
          __builtin_amdgcn_s_setprio(1);
#pragma unroll
          for (int mi = 0; mi < 4; ++mi)
#pragma unroll
            for (int ni = 0; ni < 4; ++ni)
              acc[mh * 4 + mi][ni] =
                  __builtin_amdgcn_mfma_f32_16x16x32_bf16(afr[mi], bfr[ni], acc[mh * 4 + mi][ni], 0, 0, 0);
          __builtin_amdgcn_s_setprio(0);
        }
      }
      __builtin_amdgcn_sched_barrier(0);
      __builtin_amdgcn_s_barrier();
      cur ^= 1;
    }
    const int row0 = tm * 256 + wm * 128 + ((l >> 4) << 2);
    const int col0 = tn * 256 + wn * 64 + (l & 15);
#pragma unroll
    for (int mi = 0; mi < 8; ++mi) {
#pragma unroll
      for (int j = 0; j < 4; ++j) {
        int grow = row0 + mi * 16 + j;
        if (grow < Mvalid) {
#pragma unroll
          for (int ni = 0; ni < 4; ++ni) {
            int gcol = col0 + ni * 16;
            if (gcol < Nv) {
              float vv = acc[mi][ni][j];
              int gc = cO + gcol;
              if (bias) vv += bias[gc];
              Cb[(size_t)grow * ldc + gc] = vv;
            }
          }
        }
      }
    }
  }
}

static inline int imin(int a, int b) { return a < b ? a : b; }

extern "C" void kernel_launch(void* const* d_in, const int* in_sizes, int n_in,
                              void* d_out, int out_size, void* d_ws, size_t ws_size,
                              hipStream_t stream) {
  const float* signal = (const float*)d_in[0];
  const int*   bc_idx = (const int*)d_in[1];
  const float* bc_w   = (const float*)d_in[2];
  const float* tmpl[3] = { (const float*)d_in[3], (const float*)d_in[5], (const float*)d_in[7] };
  const float* tb[3]   = { (const float*)d_in[4], (const float*)d_in[6], (const float*)d_in[8] };
  const float* Wd = (const float*)d_in[9];
  const float* bd = (const float*)d_in[10];
  float* outp = (float*)d_out;

  char* ws = (char*)d_ws;
  size_t off = 0;
  auto alloc = [&](size_t b) -> void* {
    size_t o = (off + 255) & ~(size_t)255; off = o + b; return (void*)(ws + o);
  };
  u16* sigbf = (u16*)alloc((size_t)V_N * 544 * 2);
  u16* outL0 = (u16*)alloc((size_t)V_PAD * 96 * 2);
  u16* outL1 = (u16*)alloc((size_t)V_PAD * 128 * 2);
  u16* outL2 = (u16*)alloc((size_t)V_PAD * 256 * 2);       // split hi|lo
  // per-layer frequency-domain B buffers: layout = B0(Tn*K0pad) | bins1-3 (6*Tn*K1) | B4(Tn*K0pad).
  // R11 BUG: B4 section was not counted -> overflow into the next buffer. Correct size is
  // 2*Tn*K0pad + 6*Tn*K1, plus 32*K0pad margin for the narrow-tile row over-read (Tn=96 < 128).
  u16* trotB0 = (u16*)alloc(((size_t)2 * 96 * 2752 + (size_t)6 * 96 * 5440 + 32 * 2752) * 2);
  u16* trotB1 = (u16*)alloc(((size_t)2 * 128 * 512 + (size_t)6 * 128 * 960 + 32 * 512) * 2);
  u16* trotB2 = (u16*)alloc(((size_t)2 * 128 * 640 + (size_t)6 * 128 * 1280 + 32 * 640) * 2);
  u16* wdtB   = (u16*)alloc((size_t)V_PAD * 256 * 2);
  float* gemmC = (float*)alloc((size_t)4 * V_PAD * 1024 * 4); // split-K partials
  size_t o2 = (off + 255) & ~(size_t)255;
  u16* interp = (u16*)(ws + o2);
  size_t interpElems = (ws_size > o2) ? (ws_size - o2) / 2 : 0;

  u16* trotB[3] = { trotB0, trotB1, trotB2 };

  { // fused prep: cvt | trot0 | trot1 | trot2 | wdt
    int nCvt = V_N * 544 / 4;
    int bCvt = (nCvt + 255) / 256;
    int bT0 = (96 * 5 * 136 + 96 * 32 + 255) / 256;
    int bT1 = (128 * 5 * 24 + 128 * 32 + 255) / 256;
    int bT2 = (128 * 5 * 32 + 255) / 256;
    int bWdt = (V_PAD * 128 + 255) / 256;
    int o1 = bCvt, o2b = o1 + bT0, o3 = o2b + bT1, o4 = o3 + bT2;
    prep_kernel<<<dim3(o4 + bWdt), dim3(256), 0, stream>>>(
        signal, sigbf, nCvt, tmpl[0], trotB0, tmpl[1], trotB1, tmpl[2], trotB2,
        Wd, wdtB, o1, o2b, o3, o4);
  }

  const int TnA[3] = {96, 128, 128}, CcA[3] = {544, 96, 128};
  const int nsTab[3][5] = {{2,5,5,4,2},{1,2,2,2,1},{1,2,2,2,1}};
  const int CrA[3] = {3584, V_PAD, V_PAD};
  u16* outs[3] = { outL0, outL1, outL2 };
  const u16* cursig = sigbf;
  for (int L = 0; L < 3; ++L) {
    const int Tn = TnA[L], Cc = CcA[L];
    const int C8 = Cc / 8;
    const int K0 = 5 * Cc, K0pad = ((K0 + 63) / 64) * 64;
    const int K1 = 10 * Cc;
    const int Kpad = 2 * K0pad + 3 * K1;
    const int N = 8 * Tn;
    const int* ns = nsTab[L];
    const size_t cstride = (size_t)V_PAD * N;

    GTab tg;
    int Kg5[5] = {K0pad, K1, K1, K1, K0pad};
    int Ng5[5] = {Tn, 2 * Tn, 2 * Tn, 2 * Tn, Tn};
    tg.aOff[0] = 0; tg.aOff[1] = K0pad; tg.aOff[2] = K0pad + K1;
    tg.aOff[3] = K0pad + 2 * K1; tg.aOff[4] = K0pad + 3 * K1;
    tg.bOff[0] = 0; tg.bOff[1] = Tn * K0pad;
    tg.bOff[2] = Tn * K0pad + 2 * Tn * K1;
    tg.bOff[3] = Tn * K0pad + 4 * Tn * K1;
    tg.bOff[4] = Tn * K0pad + 6 * Tn * K1;
    tg.cOff[0] = 0; tg.cOff[1] = Tn; tg.cOff[2] = 3 * Tn; tg.cOff[3] = 5 * Tn; tg.cOff[4] = 7 * Tn;
    for (int g5 = 0; g5 < 5; ++g5) {
      tg.Kg[g5] = Kg5[g5];
      tg.kch[g5] = ((Kg5[g5] / 64 + ns[g5] - 1) / ns[g5]) * 64;
      tg.ntn[g5] = 1;
      tg.Nv[g5] = Ng5[g5];
      tg.nh[g5] = (g5 == 0 || g5 == 4) ? 1 : 0;   // DC/Nyquist bins: N<=128 -> narrow tile
    }

    long crl = (long)(interpElems / (size_t)Kpad) & ~(long)255;
    int cr = (crl > (long)CrA[L]) ? CrA[L] : (int)crl;
    if (cr < 256) cr = 256;
    for (int v0 = 0; v0 < V_PAD; v0 += cr) {
      int rows = imin(cr, V_PAD - v0);
      int nv = imin(rows, V_N - v0);
      { int total = nv * 5 * C8;
        interp_fft_kernel<<<dim3((total + 255) / 256), dim3(256), 0, stream>>>(
            cursig, Cc, C8, bc_idx, bc_w, interp, v0, Kpad, K0pad, K1, total); }
      int ntm = rows / 256;
      tg.start[0] = 0;
      for (int g5 = 0; g5 < 5; ++g5) tg.start[g5 + 1] = tg.start[g5] + ns[g5] * ntm;
      gemm_grp<<<dim3(tg.start[5]), dim3(512), 0, stream>>>(
          interp, Kpad, trotB[L], gemmC + (size_t)v0 * N, N, cstride, nullptr, nv, ntm, 5, tg);
    }
    { int total = V_N * Tn;
      int ldo = (L == 2) ? 256 : ((L == 0) ? 96 : 128);
      amp_fft<<<dim3((total + 255) / 256), dim3(256), 0, stream>>>(
          gemmC, cstride, tb[L], outs[L], Tn, ldo, (L == 2) ? 1 : 0,
          ns[0], ns[1], ns[2], ns[3], ns[4], total); }
    cursig = outs[L];
  }

  GTab td;
  td.start[0] = 0; td.start[1] = 27 * 27;
  td.aOff[0] = 0; td.bOff[0] = 0; td.cOff[0] = 0;
  td.Kg[0] = 256; td.kch[0] = 256; td.ntn[0] = 27; td.Nv[0] = V_N; td.nh[0] = 0;
  for (int g5 = 1; g5 < 5; ++g5) { td.start[g5 + 1] = td.start[1]; td.aOff[g5] = 0; td.bOff[g5] = 0;
    td.cOff[g5] = 0; td.Kg[g5] = 256; td.kch[g5] = 256; td.ntn[g5] = 1; td.Nv[g5] = 0; td.nh[g5] = 0; }
  gemm_grp<<<dim3(27 * 27), dim3(512), 0, stream>>>(
      outL2, 256, wdtB, outp, V_N, 0, bd, V_N, 27, 1, td);
}

// Round 13
// 572.859 us; speedup vs baseline: 1.0044x; 1.0044x over previous
//
#include <hip/hip_runtime.h>

typedef unsigned short u16;
typedef unsigned int   u32;
typedef __bf16 bf16x8 __attribute__((ext_vector_type(8)));
typedef float  f32x4  __attribute__((ext_vector_type(4)));
typedef u32    u32x4  __attribute__((ext_vector_type(4)));
typedef u32    u32x2  __attribute__((ext_vector_type(2)));
typedef u16    u16x4  __attribute__((ext_vector_type(4)));

#define V_N   6890
#define V_PAD 6912
#define SQ2H  0.70710678118654752f

__device__ __forceinline__ float bf2f(u32 h) {
  union { u32 u; float f; } c; c.u = h << 16; return c.f;
}
__device__ __forceinline__ u16 f2bf(float f) {
  union { float f; u32 u; } c; c.f = f;
  return (u16)((c.u + 0x7fffu + ((c.u >> 16) & 1u)) >> 16);
}
__device__ __forceinline__ u32 pk(float lo, float hi) {
  return (u32)f2bf(lo) | ((u32)f2bf(hi) << 16);
}
__device__ __forceinline__ void gload_lds16(const void* g, void* l) {
  __builtin_amdgcn_global_load_lds((const __attribute__((address_space(1))) void*)g,
                                   (__attribute__((address_space(3))) void*)l, 16, 0, 0);
}

// rfft8: X[k] = sum_a x[a] e^{-2pi i k a/8}; returns Z0, (Re,Im) k=1..3, Z4.
__device__ __forceinline__ void rfft8(const float* x, float& Z0, float& Re1, float& Im1,
                                      float& Re2, float& Im2, float& Re3, float& Im3, float& Z4) {
  float s04 = x[0] + x[4], d04 = x[0] - x[4];
  float s26 = x[2] + x[6], d26 = x[2] - x[6];
  float s15 = x[1] + x[5], d15 = x[1] - x[5];
  float s37 = x[3] + x[7], d37 = x[3] - x[7];
  float e = s04 + s26, f = s15 + s37;
  Z0 = e + f; Z4 = e - f;
  Re2 = s04 - s26; Im2 = s37 - s15;
  float t1 = SQ2H * (d15 - d37), t2 = SQ2H * (d15 + d37);
  Re1 = d04 + t1; Re3 = d04 - t1;
  Im1 = -(t2 + d26); Im3 = d26 - t2;
}

// ---- template FFT worker (one (t,r,c4) element or pad-zero tail) ----
__device__ __forceinline__ void do_trot(int g, const float* __restrict__ T, u16* __restrict__ B,
                                        int Tn, int Cc, int C4, int K0pad, int K1,
                                        int total, int pad) {
  if (g >= total) {
    int g2 = g - total;
    int padTot = Tn * pad;
    if (g2 >= padTot) return;
    int p = g2 % pad; int t = g2 / pad;
    size_t b4off = (size_t)Tn * K0pad + (size_t)6 * Tn * K1;
    size_t o = (size_t)t * K0pad + (K0pad - pad) + p;
    B[o] = 0; B[b4off + o] = 0;
    return;
  }
  int c4 = g % C4; int q = g / C4;
  int r = q % 5; int t = q / 5;
  float hs[8][4];
#pragma unroll
  for (int a = 0; a < 8; ++a) {
    f32x4 va = *(const f32x4*)(T + ((size_t)((t * 5 + r) * 8 + a)) * Cc + c4 * 4);
#pragma unroll
    for (int j = 0; j < 4; ++j) hs[a][j] = va[j];
  }
  float Z0[4], Z4[4], Re[3][4], Im[3][4];
#pragma unroll
  for (int ch = 0; ch < 4; ++ch) {
    float x[8];
#pragma unroll
    for (int a = 0; a < 8; ++a) x[a] = hs[a][ch];
    float z0, r1, i1, r2, i2, r3, i3, z4;
    rfft8(x, z0, r1, i1, r2, i2, r3, i3, z4);
    Z0[ch] = z0 * 0.125f; Z4[ch] = z4 * 0.125f;
    Re[0][ch] = r1 * 0.25f; Im[0][ch] = i1 * 0.25f;
    Re[1][ch] = r2 * 0.25f; Im[1][ch] = i2 * 0.25f;
    Re[2][ch] = r3 * 0.25f; Im[2][ch] = i3 * 0.25f;
  }
  int cb = c4 * 4;
  u32x2 w0v; w0v[0] = pk(Z0[0], Z0[1]); w0v[1] = pk(Z0[2], Z0[3]);
  *(u32x2*)(B + (size_t)t * K0pad + r * Cc + cb) = w0v;
  size_t bo1 = (size_t)Tn * K0pad;
  size_t binSz = (size_t)2 * Tn * K1;
  int off = ((r * Cc + cb) << 1);
#pragma unroll
  for (int k = 0; k < 3; ++k) {
    u32x4 wr, wi;
#pragma unroll
    for (int j = 0; j < 4; ++j) {
      wr[j] = pk(Re[k][j], Im[k][j]);
      wi[j] = pk(-Im[k][j], Re[k][j]);
    }
    *(u32x4*)(B + bo1 + k * binSz + (size_t)t * K1 + off) = wr;
    *(u32x4*)(B + bo1 + k * binSz + (size_t)(Tn + t) * K1 + off) = wi;
  }
  u32x2 w4v; w4v[0] = pk(Z4[0], Z4[1]); w4v[1] = pk(Z4[2], Z4[3]);
  *(u32x2*)(B + bo1 + 3 * binSz + (size_t)t * K0pad + r * Cc + cb) = w4v;
}

// ---- prep, memory-bound half: cvt | wdt (both low-VGPR vec copies) ----
__global__ void prep_light_kernel(const float* __restrict__ signal, u16* __restrict__ sigbf,
                                  int nCvt, const float* __restrict__ Wd,
                                  u16* __restrict__ wdtB, int o1) {
  int b = blockIdx.x;
  if (b < o1) {
    int g = b * 256 + threadIdx.x;
    if (g >= nCvt) return;
    f32x4 v = *(const f32x4*)(signal + (size_t)g * 4);
    u16x4 o; o.x = f2bf(v.x); o.y = f2bf(v.y); o.z = f2bf(v.z); o.w = f2bf(v.w);
    *(u16x4*)(sigbf + (size_t)g * 4) = o;
  } else {
    int g = (b - o1) * 256 + threadIdx.x;
    if (g >= V_PAD * 128) return;
    int k = g & 127, n = g >> 7;
    float v = (n < V_N) ? Wd[(size_t)k * V_N + n] : 0.f;
    u16 hi = f2bf(v);
    wdtB[(size_t)n * 256 + k] = hi;
    wdtB[(size_t)n * 256 + 128 + k] = f2bf(v - bf2f(hi));
  }
}

// ---- prep, register-heavy half: trot L0 | trot L1 | trot L2 (homogeneous VGPR) ----
__global__ void prep_trot_kernel(const float* __restrict__ T0, u16* __restrict__ B0,
                                 const float* __restrict__ T1, u16* __restrict__ B1,
                                 const float* __restrict__ T2, u16* __restrict__ B2,
                                 int o1, int o2) {
  int b = blockIdx.x;
  if (b < o1) {
    int g = b * 256 + threadIdx.x;
    do_trot(g, T0, B0, 96, 544, 136, 2752, 5440, 96 * 5 * 136, 32);
  } else if (b < o2) {
    int g = (b - o1) * 256 + threadIdx.x;
    do_trot(g, T1, B1, 128, 96, 24, 512, 960, 128 * 5 * 24, 32);
  } else {
    int g = (b - o2) * 256 + threadIdx.x;
    do_trot(g, T2, B2, 128, 128, 32, 640, 1280, 128 * 5 * 32, 0);
  }
}

// ---- barycentric gather + interp + rfft8 over angular axis; writes A_hat sections.
//      idx/wgt rows are 24 consecutive elements (96B, 16B-aligned): vec4 loads. ----
__global__ void interp_fft_kernel(const u16* __restrict__ sig, int Cc, int C8,
                                  const int* __restrict__ idx, const float* __restrict__ wgt,
                                  u16* __restrict__ out, int v0, int Kpad, int K0pad, int K1,
                                  int total) {
  int g = blockIdx.x * 256 + threadIdx.x;
  if (g >= total) return;
  int c8 = g % C8; int q = g / C8;
  int r = q % 5; int vr = q / 5;
  size_t ib = ((size_t)((v0 + vr) * 5 + r)) * 24;
  u32x4 iv[6]; f32x4 wv[6];
  const u32x4* ip = (const u32x4*)(idx + ib);
  const f32x4* wp = (const f32x4*)(wgt + ib);
#pragma unroll
  for (int m = 0; m < 6; ++m) { iv[m] = ip[m]; wv[m] = wp[m]; }
  float xs[8][8];
#pragma unroll
  for (int a = 0; a < 8; ++a) {
    const int e = a * 3;
    int i0 = iv[e >> 2][e & 3], i1 = iv[(e + 1) >> 2][(e + 1) & 3], i2 = iv[(e + 2) >> 2][(e + 2) & 3];
    float w0 = wv[e >> 2][e & 3], w1 = wv[(e + 1) >> 2][(e + 1) & 3], w2 = wv[(e + 2) >> 2][(e + 2) & 3];
    u32x4 s0 = *(const u32x4*)(sig + (size_t)i0 * Cc + c8 * 8);
    u32x4 s1 = *(const u32x4*)(sig + (size_t)i1 * Cc + c8 * 8);
    u32x4 s2 = *(const u32x4*)(sig + (size_t)i2 * Cc + c8 * 8);
#pragma unroll
    for (int j = 0; j < 4; ++j) {
      xs[a][2 * j]     = w0 * bf2f(s0[j] & 0xffffu) + w1 * bf2f(s1[j] & 0xffffu) + w2 * bf2f(s2[j] & 0xffffu);
      xs[a][2 * j + 1] = w0 * bf2f(s0[j] >> 16)     + w1 * bf2f(s1[j] >> 16)     + w2 * bf2f(s2[j] >> 16);
    }
  }
  float Z0[8], Z4[8], Re1[8], Im1[8], Re2[8], Im2[8], Re3[8], Im3[8];
#pragma unroll
  for (int ch = 0; ch < 8; ++ch) {
    float x[8];
#pragma unroll
    for (int a = 0; a < 8; ++a) x[a] = xs[a][ch];
    rfft8(x, Z0[ch], Re1[ch], Im1[ch], Re2[ch], Im2[ch], Re3[ch], Im3[ch], Z4[ch]);
  }
  size_t rowb = (size_t)vr * Kpad;
  int cb = c8 * 8;
  u32x4 a0, a4;
#pragma unroll
  for (int p = 0; p < 4; ++p) {
    a0[p] = pk(Z0[2 * p], Z0[2 * p + 1]);
    a4[p] = pk(Z4[2 * p], Z4[2 * p + 1]);
  }
  *(u32x4*)(out + rowb + r * Cc + cb) = a0;
  *(u32x4*)(out + rowb + K0pad + 3 * K1 + r * Cc + cb) = a4;
  int off1 = K0pad + ((r * Cc + cb) << 1);
  u32x4 wa, wb;
#pragma unroll
  for (int j = 0; j < 4; ++j) { wa[j] = pk(Re1[j], Im1[j]); wb[j] = pk(Re1[4 + j], Im1[4 + j]); }
  *(u32x4*)(out + rowb + off1) = wa;
  *(u32x4*)(out + rowb + off1 + 8) = wb;
#pragma unroll
  for (int j = 0; j < 4; ++j) { wa[j] = pk(Re2[j], Im2[j]); wb[j] = pk(Re2[4 + j], Im2[4 + j]); }
  *(u32x4*)(out + rowb + off1 + K1) = wa;
  *(u32x4*)(out + rowb + off1 + K1 + 8) = wb;
#pragma unroll
  for (int j = 0; j < 4; ++j) { wa[j] = pk(Re3[j], Im3[j]); wb[j] = pk(Re3[4 + j], Im3[4 + j]); }
  *(u32x4*)(out + rowb + off1 + 2 * K1) = wa;
  *(u32x4*)(out + rowb + off1 + 2 * K1 + 8) = wb;
}

// ---- split-K reduce + 8-point iFFT + relu(+bias) + angular max; optional split-bf16 out ----
__global__ void amp_fft(const float* __restrict__ Cin, size_t cstride,
                        const float* __restrict__ bias, u16* __restrict__ out,
                        int Tn, int ldo, int split,
                        int ns0, int ns1, int ns2, int ns3, int ns4, int total) {
  int g = blockIdx.x * 256 + threadIdx.x;
  if (g >= total) return;
  int t = g % Tn, v = g / Tn;
  const int nsA[8] = {ns0, ns1, ns1, ns2, ns2, ns3, ns3, ns4};
  float sec[8];
  size_t base = (size_t)v * (8 * Tn) + t;
#pragma unroll
  for (int s = 0; s < 8; ++s) {
    const float* p = Cin + base + s * Tn;
    float a = p[0];
    for (int k = 1; k < nsA[s]; ++k) a += p[(size_t)k * cstride];
    sec[s] = a;
  }
  const float Ct[8] = {1.f, SQ2H, 0.f, -SQ2H, -1.f, -SQ2H, 0.f, SQ2H};
  const float St[8] = {0.f, SQ2H, 1.f, SQ2H, 0.f, -SQ2H, -1.f, -SQ2H};
  float m;
#pragma unroll
  for (int o = 0; o < 8; ++o) {
    float val = sec[0] + ((o & 1) ? -sec[7] : sec[7])
      + sec[1] * Ct[o]           - sec[2] * St[o]
      + sec[3] * Ct[(2 * o) & 7] - sec[4] * St[(2 * o) & 7]
      + sec[5] * Ct[(3 * o) & 7] - sec[6] * St[(3 * o) & 7];
    m = (o == 0) ? val : fmaxf(m, val);
  }
  m = fmaxf(m + bias[t], 0.f);
  u16 hi = f2bf(m);
  out[(size_t)v * ldo + t] = hi;
  if (split) out[(size_t)v * ldo + Tn + t] = f2bf(m - bf2f(hi));
}

// ---- grouped 256-row bf16 GEMM (R7-proven schedule). Per-group nh flag:
//      nh=0: 256-wide tile (2Mx4N waves, 64 MFMA/Ktile, stage 8, vmcnt(8))
//      nh=1: 128-wide tile (4Mx2N waves, 32 MFMA/Ktile, stage 6, vmcnt(6)) ----
struct GTab {
  int start[6];
  int aOff[5];
  int bOff[5];
  int cOff[5];
  int Kg[5];
  int kch[5];
  int ntn[5];
  int Nv[5];
  int nh[5];
};

__global__ __launch_bounds__(512, 2) void gemm_grp(
    const u16* __restrict__ A, int lda, const u16* __restrict__ Bbase,
    float* __restrict__ C, int ldc, size_t cstride,
    const float* __restrict__ bias, int Mvalid, int ntm, int nG, GTab tb) {
  __shared__ __align__(16) u16 lA[2][256 * 64];
  __shared__ __align__(16) u16 lB[2][256 * 64];
  const int tid = threadIdx.x;
  const int w = tid >> 6, l = tid & 63;

  const int nb = gridDim.x, bid = blockIdx.x;
  const int qq = nb >> 3, rr = nb & 7;
  const int xcd = bid & 7, ii = bid >> 3;
  const int vb = (xcd < rr ? xcd * (qq + 1) : rr * (qq + 1) + (xcd - rr) * qq) + ii;

  int gI = 0;
#pragma unroll
  for (int k = 1; k < 5; ++k) if (k < nG && vb >= tb.start[k]) gI = k;
  const int local = vb - tb.start[gI];
  const int ntnG = tb.ntn[gI];
  const int per = ntm * ntnG;
  const int s = local / per;
  const int rem = local - s * per;
  const int tm = rem / ntnG, tn = rem - tm * ntnG;
  const int Kg = tb.Kg[gI];
  const int kb = s * tb.kch[gI];
  int ke = kb + tb.kch[gI]; if (ke > Kg) ke = Kg;
  const int nt = (ke - kb + 63) >> 6;
  const int Nv = tb.Nv[gI];
  const int cO = tb.cOff[gI];
  const int nh = tb.nh[gI];
  const int ldb = Kg;
  float* Cb = C + (size_t)s * cstride;

  const u16* Ab = A + (size_t)(tm * 256) * lda + tb.aOff[gI] + kb;
  const u16* Bb = Bbase + tb.bOff[gI] + (size_t)(tn * (nh ? 128 : 256)) * ldb + kb;

  const int srow = tid >> 3;
  const int scol = (((l & 7) ^ (srow & 7)) << 3);
  u16* laBase = &lA[0][0];
  u16* lbBase = &lB[0][0];

  f32x4 acc[8][4];
#pragma unroll
  for (int i = 0; i < 8; ++i)
#pragma unroll
    for (int j = 0; j < 4; ++j) acc[i][j] = (f32x4){0.f, 0.f, 0.f, 0.f};

  const int ksel = l >> 4, swz = l & 7;
  const int kc0 = ((ksel ^ swz) << 3);
  const int kc1 = (((4 + ksel) ^ swz) << 3);

  if (nh) {
    // ---------------- narrow: 128-wide tile, 4Mx2N waves ----------------
    const int wm = w >> 1, wn = w & 1;
    const int aoffbase = (wm * 64 + (l & 15)) * 64;
    const int boffbase = (wn * 64 + (l & 15)) * 64;
    auto STAGE = [&](int buf, int k0) {
      const u16* ga = Ab + (size_t)srow * lda + k0 + scol;
      const u16* gb = Bb + (size_t)srow * ldb + k0 + scol;
      u16* la = laBase + buf * (256 * 64) + w * 512;
      u16* lb = lbBase + buf * (256 * 64) + w * 512;
#pragma unroll
      for (int i = 0; i < 4; ++i)
        gload_lds16(ga + (size_t)(i * 64) * lda, la + i * 4096);
#pragma unroll
      for (int i = 0; i < 2; ++i)
        gload_lds16(gb + (size_t)(i * 64) * ldb, lb + i * 4096);
    };
    STAGE(0, 0);
    int cur = 0;
    for (int t = 0; t < nt; ++t) {
      if (t + 1 < nt) STAGE(cur ^ 1, (t + 1) * 64);
      __builtin_amdgcn_sched_barrier(0);
      if (t + 1 < nt) { asm volatile("s_waitcnt vmcnt(6)" ::: "memory"); }
      else            { asm volatile("s_waitcnt vmcnt(0)" ::: "memory"); }
      __builtin_amdgcn_s_barrier();
      __builtin_amdgcn_sched_barrier(0);
      const u16* lab = laBase + cur * (256 * 64);
      const u16* lbb = lbBase + cur * (256 * 64);
#pragma unroll
      for (int kk = 0; kk < 2; ++kk) {
        const int kc = kk ? kc1 : kc0;
        bf16x8 bfr[4];
#pragma unroll
        for (int ni = 0; ni < 4; ++ni)
          bfr[ni] = *(const bf16x8*)&lbb[boffbase + ni * 1024 + kc];
        bf16x8 afr[4];
#pragma unroll
        for (int mi = 0; mi < 4; ++mi)
          afr[mi] = *(const bf16x8*)&lab[aoffbase + mi * 1024 + kc];
        __builtin_amdgcn_s_setprio(1);
#pragma unroll
        for (int mi = 0; mi < 4; ++mi)
#pragma unroll
          for (int ni = 0; ni < 4; ++ni)
            acc[mi][ni] =
                __builtin_amdgcn_mfma_f32_16x16x32_bf16(afr[mi], bfr[ni], acc[mi][ni], 0, 0, 0);
        __builtin_amdgcn_s_setprio(0);
      }
      __builtin_amdgcn_sched_barrier(0);
      __builtin_amdgcn_s_barrier();
      cur ^= 1;
    }
    const int row0 = tm * 256 + wm * 64 + ((l >> 4) << 2);
    const int col0 = tn * 128 + wn * 64 + (l & 15);
#pragma unroll
    for (int mi = 0; mi < 4; ++mi) {
#pragma unroll
      for (int j = 0; j < 4; ++j) {
        int grow = row0 + mi * 16 + j;
        if (grow < Mvalid) {
#pragma unroll
          for (int ni = 0; ni < 4; ++ni) {
            int gcol = col0 + ni * 16;
            if (gcol < Nv) {
              float vv = acc[mi][ni][j];
              int gc = cO + gcol;
              if (bias) vv += bias[gc];
              Cb[(size_t)grow * ldc + gc] = vv;
            }
          }
        }
      }
    }
  } else {
    // ---------------- wide: 256-wide tile, 2Mx4N waves ----------------
    const int wm = w >> 2, wn = w & 3;
    const int aoffbase = (wm * 128 + (l & 15)) * 64;
    const int boffbase = (wn * 64 + (l & 15)) * 64;
    auto STAGE = [&](int buf, int k0) {
      const u16* ga = Ab + (size_t)srow * lda + k0 + scol;
      const u16* gb = Bb + (size_t)srow * ldb + k0 + scol;
      u16* la = laBase + buf * (256 * 64) + w * 512;
      u16* lb = lbBase + buf * (256 * 64) + w * 512;
#pragma unroll
      for (int i = 0; i < 4; ++i) {
        gload_lds16(ga + (size_t)(i * 64) * lda, la + i * 4096);
        gload_lds16(gb + (size_t)(i * 64) * ldb, lb + i * 4096);
      }
    };
    STAGE(0, 0);
    int cur = 0;
    for (int t = 0; t < nt; ++t) {
      if (t + 1 < nt) STAGE(cur ^ 1, (t + 1) * 64);
      __builtin_amdgcn_sched_barrier(0);
      if (t + 1 < nt) { asm volatile("s_waitcnt vmcnt(8)" ::: "memory"); }
      else            { asm volatile("s_waitcnt vmcnt(0)" ::: "memory"); }
      __builtin_amdgcn_s_barrier();
      __builtin_amdgcn_sched_barrier(0);
      const u16* lab = laBase + cur * (256 * 64);
      const u16* lbb = lbBase + cur * (256 * 64);
#pragma unroll
      for (int kk = 0; kk < 2; ++kk) {
        const int kc = kk ? kc1 : kc0;
        bf16x8 bfr[4];
#pragma unroll
        for (int ni = 0; ni < 4; ++ni)
          bfr[ni] = *(const bf16x8*)&lbb[boffbase + ni * 1024 + kc];
#pragma unroll
        for (int mh = 0; mh < 2; ++mh) {
          bf16x8 afr[4];
#pragma unroll
          for (int mi = 0; mi < 4; ++mi)
            afr[mi] = *(const bf16x8*)&lab[aoffbase + (mh * 4 + mi) * 1024 + kc];
          __builtin_amdgcn_s_setprio(1);
#pragma unroll
          for (int mi = 0; mi < 4; ++mi)
#pragma unroll
            for (int ni = 0; ni < 4; ++ni)
              acc[mh * 4 + mi][ni] =
                  __builtin_amdgcn_mfma_f32_16x16x32_bf16(afr[mi], bfr[ni], acc[mh * 4 + mi][ni], 0, 0, 0);
          __builtin_amdgcn_s_setprio(0);
        }
      }
      __builtin_amdgcn_sched_barrier(0);
      __builtin_amdgcn_s_barrier();
      cur ^= 1;
    }
    const int row0 = tm * 256 + wm * 128 + ((l >> 4) << 2);
    const int col0 = tn * 256 + wn * 64 + (l & 15);
#pragma unroll
    for (int mi = 0; mi < 8; ++mi) {
#pragma unroll
      for (int j = 0; j < 4; ++j) {
        int grow = row0 + mi * 16 + j;
        if (grow < Mvalid) {
#pragma unroll
          for (int ni = 0; ni < 4; ++ni) {
            int gcol = col0 + ni * 16;
            if (gcol < Nv) {
              float vv = acc[mi][ni][j];
              int gc = cO + gcol;
              if (bias) vv += bias[gc];
              Cb[(size_t)grow * ldc + gc] = vv;
            }
          }
        }
      }
    }
  }
}

static inline int imin(int a, int b) { return a < b ? a : b; }

extern "C" void kernel_launch(void* const* d_in, const int* in_sizes, int n_in,
                              void* d_out, int out_size, void* d_ws, size_t ws_size,
                              hipStream_t stream) {
  const float* signal = (const float*)d_in[0];
  const int*   bc_idx = (const int*)d_in[1];
  const float* bc_w   = (const float*)d_in[2];
  const float* tmpl[3] = { (const float*)d_in[3], (const float*)d_in[5], (const float*)d_in[7] };
  const float* tb[3]   = { (const float*)d_in[4], (const float*)d_in[6], (const float*)d_in[8] };
  const float* Wd = (const float*)d_in[9];
  const float* bd = (const float*)d_in[10];
  float* outp = (float*)d_out;

  char* ws = (char*)d_ws;
  size_t off = 0;
  auto alloc = [&](size_t b) -> void* {
    size_t o = (off + 255) & ~(size_t)255; off = o + b; return (void*)(ws + o);
  };
  u16* sigbf = (u16*)alloc((size_t)V_N * 544 * 2);
  u16* outL0 = (u16*)alloc((size_t)V_PAD * 96 * 2);
  u16* outL1 = (u16*)alloc((size_t)V_PAD * 128 * 2);
  u16* outL2 = (u16*)alloc((size_t)V_PAD * 256 * 2);       // split hi|lo
  // per-layer frequency-domain B: B0(Tn*K0pad) | bins1-3 (6*Tn*K1) | B4(Tn*K0pad)
  // + 32*K0pad margin for the narrow-tile row over-read when Tn=96 < 128.
  u16* trotB0 = (u16*)alloc(((size_t)2 * 96 * 2752 + (size_t)6 * 96 * 5440 + 32 * 2752) * 2);
  u16* trotB1 = (u16*)alloc(((size_t)2 * 128 * 512 + (size_t)6 * 128 * 960 + 32 * 512) * 2);
  u16* trotB2 = (u16*)alloc(((size_t)2 * 128 * 640 + (size_t)6 * 128 * 1280 + 32 * 640) * 2);
  u16* wdtB   = (u16*)alloc((size_t)V_PAD * 256 * 2);
  float* gemmC = (float*)alloc((size_t)4 * V_PAD * 1024 * 4); // split-K partials
  size_t o2 = (off + 255) & ~(size_t)255;
  u16* interp = (u16*)(ws + o2);
  size_t interpElems = (ws_size > o2) ? (ws_size - o2) / 2 : 0;

  u16* trotB[3] = { trotB0, trotB1, trotB2 };

  { // prep split by register class (R12 post-mortem: fused prep inherits trot's
    // VGPR count -> memory-bound cvt/wdt lose occupancy; keep pressure homogeneous)
    int nCvt = V_N * 544 / 4;
    int bCvt = (nCvt + 255) / 256;
    int bWdt = (V_PAD * 128 + 255) / 256;
    prep_light_kernel<<<dim3(bCvt + bWdt), dim3(256), 0, stream>>>(
        signal, sigbf, nCvt, Wd, wdtB, bCvt);
    int bT0 = (96 * 5 * 136 + 96 * 32 + 255) / 256;
    int bT1 = (128 * 5 * 24 + 128 * 32 + 255) / 256;
    int bT2 = (128 * 5 * 32 + 255) / 256;
    prep_trot_kernel<<<dim3(bT0 + bT1 + bT2), dim3(256), 0, stream>>>(
        tmpl[0], trotB0, tmpl[1], trotB1, tmpl[2], trotB2, bT0, bT0 + bT1);
  }

  const int TnA[3] = {96, 128, 128}, CcA[3] = {544, 96, 128};
  const int nsTab[3][5] = {{2,5,5,4,2},{1,2,2,2,1},{1,2,2,2,1}};
  const int CrA[3] = {3584, V_PAD, V_PAD};
  u16* outs[3] = { outL0, outL1, outL2 };
  const u16* cursig = sigbf;
  for (int L = 0; L < 3; ++L) {
    const int Tn = TnA[L], Cc = CcA[L];
    const int C8 = Cc / 8;
    const int K0 = 5 * Cc, K0pad = ((K0 + 63) / 64) * 64;
    const int K1 = 10 * Cc;
    const int Kpad = 2 * K0pad + 3 * K1;
    const int N = 8 * Tn;
    const int* ns = nsTab[L];
    const size_t cstride = (size_t)V_PAD * N;

    GTab tg;
    int Kg5[5] = {K0pad, K1, K1, K1, K0pad};
    int Ng5[5] = {Tn, 2 * Tn, 2 * Tn, 2 * Tn, Tn};
    tg.aOff[0] = 0; tg.aOff[1] = K0pad; tg.aOff[2] = K0pad + K1;
    tg.aOff[3] = K0pad + 2 * K1; tg.aOff[4] = K0pad + 3 * K1;
    tg.bOff[0] = 0; tg.bOff[1] = Tn * K0pad;
    tg.bOff[2] = Tn * K0pad + 2 * Tn * K1;
    tg.bOff[3] = Tn * K0pad + 4 * Tn * K1;
    tg.bOff[4] = Tn * K0pad + 6 * Tn * K1;
    tg.cOff[0] = 0; tg.cOff[1] = Tn; tg.cOff[2] = 3 * Tn; tg.cOff[3] = 5 * Tn; tg.cOff[4] = 7 * Tn;
    for (int g5 = 0; g5 < 5; ++g5) {
      tg.Kg[g5] = Kg5[g5];
      tg.kch[g5] = ((Kg5[g5] / 64 + ns[g5] - 1) / ns[g5]) * 64;
      tg.ntn[g5] = 1;
      tg.Nv[g5] = Ng5[g5];
      tg.nh[g5] = (g5 == 0 || g5 == 4) ? 1 : 0;   // DC/Nyquist bins: N<=128 -> narrow tile
    }

    long crl = (long)(interpElems / (size_t)Kpad) & ~(long)255;
    int cr = (crl > (long)CrA[L]) ? CrA[L] : (int)crl;
    if (cr < 256) cr = 256;
    for (int v0 = 0; v0 < V_PAD; v0 += cr) {
      int rows = imin(cr, V_PAD - v0);
      int nv = imin(rows, V_N - v0);
      { int total = nv * 5 * C8;
        interp_fft_kernel<<<dim3((total + 255) / 256), dim3(256), 0, stream>>>(
            cursig, Cc, C8, bc_idx, bc_w, interp, v0, Kpad, K0pad, K1, total); }
      int ntm = rows / 256;
      tg.start[0] = 0;
      for (int g5 = 0; g5 < 5; ++g5) tg.start[g5 + 1] = tg.start[g5] + ns[g5] * ntm;
      gemm_grp<<<dim3(tg.start[5]), dim3(512), 0, stream>>>(
          interp, Kpad, trotB[L], gemmC + (size_t)v0 * N, N, cstride, nullptr, nv, ntm, 5, tg);
    }
    { int total = V_N * Tn;
      int ldo = (L == 2) ? 256 : ((L == 0) ? 96 : 128);
      amp_fft<<<dim3((total + 255) / 256), dim3(256), 0, stream>>>(
          gemmC, cstride, tb[L], outs[L], Tn, ldo, (L == 2) ? 1 : 0,
          ns[0], ns[1], ns[2], ns[3], ns[4], total); }
    cursig = outs[L];
  }

  GTab td;
  td.start[0] = 0; td.start[1] = 27 * 27;
  td.aOff[0] = 0; td.bOff[0] = 0; td.cOff[0] = 0;
  td.Kg[0] = 256; td.kch[0] = 256; td.ntn[0] = 27; td.Nv[0] = V_N; td.nh[0] = 0;
  for (int g5 = 1; g5 < 5; ++g5) { td.start[g5 + 1] = td.start[1]; td.aOff[g5] = 0; td.bOff[g5] = 0;
    td.cOff[g5] = 0; td.Kg[g5] = 256; td.kch[g5] = 256; td.ntn[g5] = 1; td.Nv[g5] = 0; td.nh[g5] = 0; }
  gemm_grp<<<dim3(27 * 27), dim3(512), 0, stream>>>(
      outL2, 256, wdtB, outp, V_N, 0, bd, V_N, 27, 1, td);
}